// Round 1
// baseline (37.639 us; speedup 1.0000x reference)
//
#include <hip/hip_runtime.h>
#include <math.h>

// RMSPE loss with optimal source permutation (n=5), one thread per sample.
// Assignment min via subset DP (Held-Karp), fully unrolled -> registers only.

#define NSRC 5

__global__ __launch_bounds__(256) void rmspe_kernel(const float* __restrict__ pred,
                                                    const float* __restrict__ tgt,
                                                    float* __restrict__ out,
                                                    int B) {
    const float PI     = 3.14159265358979323846f;
    const float INV_PI = 0.31830988618379067154f;

    int b = blockIdx.x * blockDim.x + threadIdx.x;
    float val = 0.0f;

    if (b < B) {
        const float* p = pred + (size_t)b * NSRC;
        const float* t = tgt  + (size_t)b * NSRC;
        float pr[NSRC], tg[NSRC];
#pragma unroll
        for (int i = 0; i < NSRC; ++i) { pr[i] = p[i]; tg[i] = t[i]; }

        // c[i][j] = wrap(pred_i - tgt_j)^2, wrap into [-pi/2, pi/2)
        float c[NSRC][NSRC];
#pragma unroll
        for (int i = 0; i < NSRC; ++i) {
#pragma unroll
            for (int j = 0; j < NSRC; ++j) {
                float x = pr[i] - tg[j];
                // (x + pi/2) mod pi - pi/2  ==  x - pi*floor(x/pi + 0.5)
                float d = x - PI * floorf(fmaf(x, INV_PI, 0.5f));
                c[i][j] = d * d;
            }
        }

        // Held-Karp over column subsets: dp[mask] = min cost of assigning
        // rows 0..popcount(mask)-1 to the columns in `mask`.
        float dp[1 << NSRC];
        dp[0] = 0.0f;
#pragma unroll
        for (int mask = 1; mask < (1 << NSRC); ++mask) {
            const int i = __popc(mask) - 1;   // row index (compile-time after unroll)
            float best = 3.4e38f;
#pragma unroll
            for (int j = 0; j < NSRC; ++j) {
                if (mask & (1 << j)) {
                    float cand = dp[mask ^ (1 << j)] + c[i][j];
                    best = fminf(best, cand);
                }
            }
            dp[mask] = best;
        }

        val = sqrtf(dp[(1 << NSRC) - 1] * (1.0f / NSRC));
    }

    // 64-lane wave reduction
#pragma unroll
    for (int off = 32; off > 0; off >>= 1)
        val += __shfl_down(val, off, 64);

    __shared__ float wsum[4];  // 256 threads = 4 waves
    const int lane = threadIdx.x & 63;
    const int wid  = threadIdx.x >> 6;
    if (lane == 0) wsum[wid] = val;
    __syncthreads();
    if (threadIdx.x == 0) {
        float s = wsum[0] + wsum[1] + wsum[2] + wsum[3];
        atomicAdd(out, s);
    }
}

extern "C" void kernel_launch(void* const* d_in, const int* in_sizes, int n_in,
                              void* d_out, int out_size, void* d_ws, size_t ws_size,
                              hipStream_t stream) {
    const float* pred = (const float*)d_in[0];
    const float* tgt  = (const float*)d_in[1];
    float* out = (float*)d_out;

    const int B = in_sizes[0] / NSRC;

    // Harness does NOT re-poison d_out between timed replays; we accumulate
    // with atomics, so zero it first (async memset is graph-capture safe).
    hipMemsetAsync(d_out, 0, sizeof(float), stream);

    const int threads = 256;
    const int blocks  = (B + threads - 1) / threads;
    rmspe_kernel<<<blocks, threads, 0, stream>>>(pred, tgt, out, B);
}

// Round 2
// 11.860 us; speedup vs baseline: 3.1736x; 3.1736x over previous
//
#include <hip/hip_runtime.h>
#include <math.h>

// RMSPE loss with optimal source permutation (n=5).
// Assignment min via subset DP (Held-Karp), fully unrolled -> registers only.
// Two-kernel reduction, plain stores only (no memset / atomics needed:
// every output byte is overwritten every call).

#define NSRC 5

__device__ __forceinline__ float sample_rmspe(const float pr[NSRC], const float tg[NSRC]) {
    const float PI     = 3.14159265358979323846f;
    const float INV_PI = 0.31830988618379067154f;

    // c[i][j] = wrap(pred_i - tgt_j)^2, wrap into [-pi/2, pi/2)
    float c[NSRC][NSRC];
#pragma unroll
    for (int i = 0; i < NSRC; ++i) {
#pragma unroll
        for (int j = 0; j < NSRC; ++j) {
            float x = pr[i] - tg[j];
            // (x + pi/2) mod pi - pi/2  ==  x - pi*floor(x/pi + 0.5)
            float d = x - PI * floorf(fmaf(x, INV_PI, 0.5f));
            c[i][j] = d * d;
        }
    }

    // Held-Karp over column subsets: dp[mask] = min cost of assigning
    // rows 0..popcount(mask)-1 to the columns in `mask`. Fully unrolled,
    // all indices compile-time -> registers (no scratch).
    float dp[1 << NSRC];
    dp[0] = 0.0f;
#pragma unroll
    for (int mask = 1; mask < (1 << NSRC); ++mask) {
        const int i = __popc(mask) - 1;
        float best = 3.4e38f;
#pragma unroll
        for (int j = 0; j < NSRC; ++j) {
            if (mask & (1 << j)) {
                float cand = dp[mask ^ (1 << j)] + c[i][j];
                best = fminf(best, cand);
            }
        }
        dp[mask] = best;
    }
    return sqrtf(dp[(1 << NSRC) - 1] * (1.0f / NSRC));
}

// Kernel 1: each thread handles 4 samples (20 floats = 5 x float4, 16B-aligned
// since per-thread stride is 80B). One partial per block, plain store.
__global__ __launch_bounds__(256) void rmspe_partial(const float4* __restrict__ pred4,
                                                     const float4* __restrict__ tgt4,
                                                     float* __restrict__ partial,
                                                     int nquad, int B,
                                                     const float* __restrict__ pred,
                                                     const float* __restrict__ tgt) {
    float val = 0.0f;
    const int stride = gridDim.x * blockDim.x;
    for (int q = blockIdx.x * blockDim.x + threadIdx.x; q < nquad; q += stride) {
        const float4* pp = pred4 + (size_t)q * NSRC;
        const float4* tp = tgt4  + (size_t)q * NSRC;
        float4 p0 = pp[0], p1 = pp[1], p2 = pp[2], p3 = pp[3], p4 = pp[4];
        float4 t0 = tp[0], t1 = tp[1], t2 = tp[2], t3 = tp[3], t4 = tp[4];
        float pf[20] = {p0.x,p0.y,p0.z,p0.w, p1.x,p1.y,p1.z,p1.w,
                        p2.x,p2.y,p2.z,p2.w, p3.x,p3.y,p3.z,p3.w,
                        p4.x,p4.y,p4.z,p4.w};
        float tf[20] = {t0.x,t0.y,t0.z,t0.w, t1.x,t1.y,t1.z,t1.w,
                        t2.x,t2.y,t2.z,t2.w, t3.x,t3.y,t3.z,t3.w,
                        t4.x,t4.y,t4.z,t4.w};
#pragma unroll
        for (int s = 0; s < 4; ++s)
            val += sample_rmspe(&pf[s * NSRC], &tf[s * NSRC]);
    }

    // Scalar tail (B % 4 samples) handled by the first few global threads.
    const int tail_start = nquad * 4;
    const int gtid = blockIdx.x * blockDim.x + threadIdx.x;
    if (tail_start + gtid < B) {
        float pr[NSRC], tg[NSRC];
#pragma unroll
        for (int i = 0; i < NSRC; ++i) {
            pr[i] = pred[(size_t)(tail_start + gtid) * NSRC + i];
            tg[i] = tgt [(size_t)(tail_start + gtid) * NSRC + i];
        }
        val += sample_rmspe(pr, tg);
    }

    // 64-lane wave reduction
#pragma unroll
    for (int off = 32; off > 0; off >>= 1)
        val += __shfl_down(val, off, 64);

    __shared__ float wsum[4];  // 256 threads = 4 waves
    const int lane = threadIdx.x & 63;
    const int wid  = threadIdx.x >> 6;
    if (lane == 0) wsum[wid] = val;
    __syncthreads();
    if (threadIdx.x == 0)
        partial[blockIdx.x] = wsum[0] + wsum[1] + wsum[2] + wsum[3];
}

// Kernel 2: single block reduces the per-block partials; plain store to out.
__global__ __launch_bounds__(256) void rmspe_reduce(const float* __restrict__ partial,
                                                    int n, float* __restrict__ out) {
    float v = 0.0f;
    for (int i = threadIdx.x; i < n; i += 256) v += partial[i];
#pragma unroll
    for (int off = 32; off > 0; off >>= 1)
        v += __shfl_down(v, off, 64);
    __shared__ float wsum[4];
    const int lane = threadIdx.x & 63;
    const int wid  = threadIdx.x >> 6;
    if (lane == 0) wsum[wid] = v;
    __syncthreads();
    if (threadIdx.x == 0)
        out[0] = wsum[0] + wsum[1] + wsum[2] + wsum[3];
}

extern "C" void kernel_launch(void* const* d_in, const int* in_sizes, int n_in,
                              void* d_out, int out_size, void* d_ws, size_t ws_size,
                              hipStream_t stream) {
    const float* pred = (const float*)d_in[0];
    const float* tgt  = (const float*)d_in[1];
    float* out = (float*)d_out;
    float* partial = (float*)d_ws;

    const int B = in_sizes[0] / NSRC;
    const int nquad = B / 4;

    const int threads = 256;
    int blocks = (nquad + threads - 1) / threads;
    if (blocks > 2048) blocks = 2048;
    if (blocks < 1) blocks = 1;

    rmspe_partial<<<blocks, threads, 0, stream>>>(
        (const float4*)pred, (const float4*)tgt, partial, nquad, B, pred, tgt);
    rmspe_reduce<<<1, threads, 0, stream>>>(partial, blocks, out);
}